// Round 3
// baseline (12.002 us; speedup 1.0000x reference)
//
#include <hip/hip_runtime.h>
#include <hip/hip_bf16.h>

// Embedding gather with OOV handling.
// out[r][d] = (idx[r] >= VOCAB) ? oov[d] : emb[idx[r]][d]
// D = 200 floats = 50 float4 per row; rows are 800B => 16B aligned.
//
// R3: ELEMS 4 -> 8 (8 independent gathers in flight per thread).
// R2 (ELEMS=4) gave 18.1 -> 11.9 us confirming latency-bound gather chain;
// this doubles memory-level parallelism again. n_vec = 1,638,400 = 800 * 2048
// exactly, so the guard never fires but is kept for generality.

typedef float f32x4 __attribute__((ext_vector_type(4)));

#define ELEMS 8
#define BLOCK 256

__global__ void embed_gather_kernel(const int* __restrict__ indices,
                                    const f32x4* __restrict__ emb,
                                    const f32x4* __restrict__ oov,
                                    f32x4* __restrict__ out,
                                    int n_vec,      // total float4 elements in output
                                    int vocab) {
    int base = blockIdx.x * (BLOCK * ELEMS) + threadIdx.x;

    int   idx[ELEMS];
    int   off[ELEMS];
    f32x4 val[ELEMS];

    // Phase 1: issue all index loads (independent, L1-hot broadcast)
    #pragma unroll
    for (int k = 0; k < ELEMS; ++k) {
        int i = base + k * BLOCK;
        int ii = (i < n_vec) ? i : 0;
        int row = ii / 50;          // magic-mul, cheap
        off[k] = ii - row * 50;
        idx[k] = indices[row];
    }

    // Phase 2: issue all gather loads (independent -> 8 outstanding vmem ops)
    #pragma unroll
    for (int k = 0; k < ELEMS; ++k) {
        const f32x4* src = (idx[k] >= vocab)
                         ? (oov + off[k])
                         : (emb + (long long)idx[k] * 50 + off[k]);
        val[k] = *src;
    }

    // Phase 3: streaming stores (write-only output, bypass cache)
    #pragma unroll
    for (int k = 0; k < ELEMS; ++k) {
        int i = base + k * BLOCK;
        if (i < n_vec) {
            __builtin_nontemporal_store(val[k], out + i);
        }
    }
}

extern "C" void kernel_launch(void* const* d_in, const int* in_sizes, int n_in,
                              void* d_out, int out_size, void* d_ws, size_t ws_size,
                              hipStream_t stream) {
    const int*   indices = (const int*)d_in[0];
    const float* emb     = (const float*)d_in[1];
    const float* oov     = (const float*)d_in[2];
    float*       out     = (float*)d_out;

    const int D      = in_sizes[2];            // 200
    const int vocab  = in_sizes[1] / D;        // 100000
    const int n_vec  = out_size / 4;           // float4 count

    const int grid = (n_vec + BLOCK * ELEMS - 1) / (BLOCK * ELEMS);
    embed_gather_kernel<<<grid, BLOCK, 0, stream>>>(
        indices,
        (const f32x4*)emb,
        (const f32x4*)oov,
        (f32x4*)out,
        n_vec, vocab);
}